// Round 14
// baseline (217.382 us; speedup 1.0000x reference)
//
#include <hip/hip_runtime.h>
#include <hip/hip_bf16.h>

#define L_TOT (1 << 18)       // 262144 positions
#define L_SHIFT 18
#define NHEAD 8
#define DHEAD 16
#define DMODEL 128
#define EPSF 1e-6f

typedef float f32x4 __attribute__((ext_vector_type(4)));
typedef short bf16x8 __attribute__((ext_vector_type(8)));

__device__ __forceinline__ float frcp(float x) { return __builtin_amdgcn_rcpf(x); }
__device__ __forceinline__ float sigm(float x) { return frcp(1.0f + __expf(-x)); }
__device__ __forceinline__ unsigned short f2bf(float f) {
    return (unsigned short)((__float_as_uint(f) + 0x8000u) >> 16);
}

// sum across each aligned 4-lane quad (lanes s=0..3 share one l), bcast to all 4
__device__ __forceinline__ float qsum(float x) {
    x += __int_as_float(__builtin_amdgcn_update_dpp(0, __float_as_int(x), 0xB1, 0xf, 0xf, true)); // xor1
    x += __int_as_float(__builtin_amdgcn_update_dpp(0, __float_as_int(x), 0x4E, 0xf, 0xf, true)); // xor2
    return x;
}

// one 16x16x32 MFMA k-step of the kv outer product: A = sigm(K)*w, B = V
__device__ __forceinline__ f32x4 kv_mfma(const float* __restrict__ Kp,
                                         const float* __restrict__ Vp,
                                         float4 wa, float4 wb, f32x4 acc) {
    const float4 ka = *(const float4*)Kp;
    const float4 kb = *(const float4*)(Kp + 4);
    const float4 va = *(const float4*)Vp;
    const float4 vb = *(const float4*)(Vp + 4);
    bf16x8 af, bvf;
    af[0] = (short)f2bf(sigm(ka.x) * wa.x);
    af[1] = (short)f2bf(sigm(ka.y) * wa.y);
    af[2] = (short)f2bf(sigm(ka.z) * wa.z);
    af[3] = (short)f2bf(sigm(ka.w) * wa.w);
    af[4] = (short)f2bf(sigm(kb.x) * wb.x);
    af[5] = (short)f2bf(sigm(kb.y) * wb.y);
    af[6] = (short)f2bf(sigm(kb.z) * wb.z);
    af[7] = (short)f2bf(sigm(kb.w) * wb.w);
    bvf[0] = (short)f2bf(va.x);
    bvf[1] = (short)f2bf(va.y);
    bvf[2] = (short)f2bf(va.z);
    bvf[3] = (short)f2bf(va.w);
    bvf[4] = (short)f2bf(vb.x);
    bvf[5] = (short)f2bf(vb.y);
    bvf[6] = (short)f2bf(vb.z);
    bvf[7] = (short)f2bf(vb.w);
    return __builtin_amdgcn_mfma_f32_16x16x32_bf16(af, bvf, acc, 0, 0, 0);
}

// ---------------------------------------------------------------------------
// K12 (fused k1+k2): per chunk of 64 l's — phase 1 = R8 stats body (w -> LDS,
// scale -> global, sumexp partial in regs); phase 2 = k2 MFMA body (K re-read
// from L2, w from LDS, V from HBM), kv accumulated in registers across the
// 4 chunks. wbuf global buffer and the separate k2 dispatch are ELIMINATED.
// 1024 blocks x 256 thr; wave wv owns heads 2wv, 2wv+1 in phase 2.
// ---------------------------------------------------------------------------
__global__ __launch_bounds__(256) void k12_fused(
        const float* __restrict__ Q, const float* __restrict__ K,
        const float* __restrict__ V,
        float* __restrict__ scale_o, float* __restrict__ sep,
        float* __restrict__ parts) {
    __shared__ float wlds[8][64];
    __shared__ float hredl[4][8];

    const int t = threadIdx.x;
    const int b = blockIdx.x;
    const int c = t >> 2;              // 0..63: which l within chunk
    const int s = t & 3;               // d-slice
    const int lane = t & 63;
    const int wv = t >> 6;
    const int lq = lane & 15, lh = lane >> 4;
    const int h0 = 2 * wv, h1 = 2 * wv + 1;

    float accse0 = 0.f, accse1 = 0.f;               // sumexp partials
    f32x4 acc0 = {0.f, 0.f, 0.f, 0.f};             // kv partial, head h0
    f32x4 acc1 = {0.f, 0.f, 0.f, 0.f};             // kv partial, head h1

    for (int ch = 0; ch < 4; ++ch) {
        const int l0 = b * 256 + ch * 64;
        const int l = l0 + c;

        // ================= phase 1: stats (R8 body) =================
        float qv[32], kvv[32];
#pragma unroll
        for (int h = 0; h < 8; ++h)
#pragma unroll
            for (int r = 0; r < 4; ++r) {
                const int p = h * 16 + s * 4 + r;
                qv[h * 4 + r]  = Q[(p << L_SHIFT) + l];
                kvv[h * 4 + r] = K[(p << L_SHIFT) + l];
            }

        unsigned a[32];
#pragma unroll
        for (int i = 0; i < 32; ++i) {
            const unsigned qu = __float_as_uint(sigm(qv[i])) + 0x8000u;
            const unsigned ku = __float_as_uint(sigm(kvv[i])) + 0x8000u;
            a[i] = __builtin_amdgcn_perm(ku, qu, 0x07060302u);
        }

        float ks[4] = {0.f, 0.f, 0.f, 0.f}, qs[4] = {0.f, 0.f, 0.f, 0.f};
#pragma unroll
        for (int h = 0; h < 8; ++h)
#pragma unroll
            for (int j = 0; j < 4; ++j) {
                const unsigned u = a[h * 4 + j];
                qs[j] += __uint_as_float(u << 16);
                ks[j] += __uint_as_float(u & 0xffff0000u);
            }

        float kse[4], qse[4];
#pragma unroll
        for (int j = 0; j < 4; ++j) { kse[j] = ks[j] + EPSF; qse[j] = qs[j] + EPSF; }

        float si[8], so[8];
#pragma unroll
        for (int h = 0; h < 8; ++h) {
            float aq = 0.f, ak = 0.f;
#pragma unroll
            for (int j = 0; j < 4; ++j) {
                const unsigned u = a[h * 4 + j];
                aq += __uint_as_float(u << 16) * kse[j];
                ak += __uint_as_float(u & 0xffff0000u) * qse[j];
            }
            si[h] = frcp(qsum(aq));
            so[h] = frcp(qsum(ak));
        }

        float kso[4] = {0.f, 0.f, 0.f, 0.f}, qsi[4] = {0.f, 0.f, 0.f, 0.f};
#pragma unroll
        for (int h = 0; h < 8; ++h)
#pragma unroll
            for (int j = 0; j < 4; ++j) {
                const unsigned u = a[h * 4 + j];
                kso[j] += __uint_as_float(u & 0xffff0000u) * so[h];
                qsi[j] += __uint_as_float(u << 16) * si[h];
            }
#pragma unroll
        for (int j = 0; j < 4; ++j) { kse[j] = kso[j] + EPSF; qse[j] = qsi[j] + EPSF; }

        float e2[2], sc2[2];
#pragma unroll
        for (int h = 0; h < 8; ++h) {
            float aq = 0.f, ak = 0.f;
#pragma unroll
            for (int j = 0; j < 4; ++j) {
                const unsigned u = a[h * 4 + j];
                aq += __uint_as_float(u << 16) * kse[j];
                ak += __uint_as_float(u & 0xffff0000u) * qse[j];
            }
            const float ck = qsum(aq);
            float cs = qsum(ak);
            if ((h >> 1) == s) {
                cs = fminf(fmaxf(cs, -1.f), 1.f);
                e2[h & 1] = __expf(cs);
                sc2[h & 1] = sigm(ck) * si[h];
            }
        }

        scale_o[((2 * s + 0) << L_SHIFT) + l] = sc2[0];
        scale_o[((2 * s + 1) << L_SHIFT) + l] = sc2[1];
        wlds[2 * s + 0][c] = e2[0];
        wlds[2 * s + 1][c] = e2[1];
        accse0 += e2[0];
        accse1 += e2[1];
        __syncthreads();                 // wlds ready for phase 2

        // ================= phase 2: kv MFMA (k2 body) =================
#pragma unroll
        for (int ksr = 0; ksr < 2; ++ksr) {
            const int lo = l0 + ksr * 32 + lh * 8;
            const int wo = ksr * 32 + lh * 8;
            {
                const float4 wa = *(const float4*)&wlds[h0][wo];
                const float4 wb = *(const float4*)&wlds[h0][wo + 4];
                acc0 = kv_mfma(&K[((h0 * DHEAD + lq) << L_SHIFT) + lo],
                               &V[((h0 * DHEAD + lq) << L_SHIFT) + lo],
                               wa, wb, acc0);
            }
            {
                const float4 wa = *(const float4*)&wlds[h1][wo];
                const float4 wb = *(const float4*)&wlds[h1][wo + 4];
                acc1 = kv_mfma(&K[((h1 * DHEAD + lq) << L_SHIFT) + lo],
                               &V[((h1 * DHEAD + lq) << L_SHIFT) + lo],
                               wa, wb, acc1);
            }
        }
        __syncthreads();                 // wlds consumed; next chunk may overwrite
    }

    // ---- kv partials: parts[(b*8+h)*256 + d*16 + m] ----
#pragma unroll
    for (int r = 0; r < 4; ++r) {
        parts[((b * 8 + h0) << 8) + (lh * 4 + r) * 16 + lq] = acc0[r];
        parts[((b * 8 + h1) << 8) + (lh * 4 + r) * 16 + lq] = acc1[r];
    }

    // ---- block sumexp partials ----
    float v0 = accse0, v1 = accse1;
    v0 += __shfl_xor(v0, 4, 64);  v1 += __shfl_xor(v1, 4, 64);
    v0 += __shfl_xor(v0, 8, 64);  v1 += __shfl_xor(v1, 8, 64);
    v0 += __shfl_xor(v0, 16, 64); v1 += __shfl_xor(v1, 16, 64);
    v0 += __shfl_xor(v0, 32, 64); v1 += __shfl_xor(v1, 32, 64);
    if ((t & 63) < 4) {
        hredl[wv][2 * s + 0] = v0;
        hredl[wv][2 * s + 1] = v1;
    }
    __syncthreads();
    if (t < 8)
        sep[b * 8 + t] = hredl[0][t] + hredl[1][t] + hredl[2][t] + hredl[3][t];
}

// ---------------------------------------------------------------------------
// K3: reduce sep -> sumexp; reduce parts (1024 blocks, fixed order) -> kv;
// emit Wkv as bf16-packed pairs wkvb[dim][p/2]. 8 blocks x 256 threads.
// ---------------------------------------------------------------------------
__global__ __launch_bounds__(256) void k3_wkv(
        const float* __restrict__ Wg, const float* __restrict__ parts,
        const float* __restrict__ sep, unsigned* __restrict__ wkvb) {
    const int hb = blockIdx.x;
    const int t = threadIdx.x;
    __shared__ float kvf[256];
    __shared__ float redl[4];

    float p = 0.f;
#pragma unroll
    for (int i = 0; i < 4; ++i) p += sep[(t + i * 256) * 8 + hb];   // 1024 blocks
#pragma unroll
    for (int o = 32; o >= 1; o >>= 1) p += __shfl_xor(p, o, 64);
    if ((t & 63) == 0) redl[t >> 6] = p;

    float ka0 = 0.f, ka1 = 0.f, ka2 = 0.f, ka3 = 0.f;
    for (int j = 0; j < 1024; j += 4) {
        ka0 += parts[(((j + 0) * 8 + hb) << 8) + t];
        ka1 += parts[(((j + 1) * 8 + hb) << 8) + t];
        ka2 += parts[(((j + 2) * 8 + hb) << 8) + t];
        ka3 += parts[(((j + 3) * 8 + hb) << 8) + t];
    }
    const float kacc = (ka0 + ka1) + (ka2 + ka3);

    __syncthreads();
    const float s = (float)L_TOT / (redl[0] + redl[1] + redl[2] + redl[3]);
    kvf[t] = kacc * s;
    __syncthreads();

#pragma unroll
    for (int i = 0; i < 4; ++i) {
        const int j = t + i * 256;              // 0..1023
        const int dim = j & 127, prp = j >> 7;  // prp: 0..7 (pr pairs)
        float a0 = 0.f, a1 = 0.f;
#pragma unroll
        for (int mm = 0; mm < 16; ++mm) {
            const float wv = Wg[dim * 128 + hb * 16 + mm];
            a0 += wv * kvf[(2 * prp) * 16 + mm];
            a1 += wv * kvf[(2 * prp + 1) * 16 + mm];
        }
        wkvb[dim * 64 + hb * 8 + prp] = ((unsigned)f2bf(a1) << 16) | f2bf(a0);
    }
}

// ---------------------------------------------------------------------------
// K4 (MFMA): out[dim,l] = b[dim] + sum_p Wkv[dim][p] * g[p][l]
// ---------------------------------------------------------------------------
__global__ __launch_bounds__(256) void k4_mfma(
        const float* __restrict__ Q, const float* __restrict__ scale_g,
        const unsigned* __restrict__ wkvb, const float* __restrict__ bg,
        float* __restrict__ out) {
    __shared__ unsigned A_lds[128 * 68];     // 34.8 KB
    __shared__ float bias[128];
    const int t = threadIdx.x;

    // stage packed Wkv into LDS
#pragma unroll
    for (int i = 0; i < 8; ++i) {
        const int idx4 = t + i * 256;        // 0..2047 uint4's
        const uint4 v = ((const uint4*)wkvb)[idx4];
        const int row = idx4 >> 4, c4 = idx4 & 15;
        *(uint4*)&A_lds[row * 68 + c4 * 4] = v;
    }
    if (t < 128) bias[t] = bg[t];
    __syncthreads();

    const int w = t >> 6, lane = t & 63;
    const int lq = lane & 15, lh = lane >> 4;

#pragma unroll
    for (int ci = 0; ci < 2; ++ci) {
        const int l = blockIdx.x * 128 + ci * 64 + w * 16 + lq;

        // load Q + scale for all 4 K-steps
        float qv[4][8];
        float scv[4];
#pragma unroll
        for (int ks = 0; ks < 4; ++ks) {
            scv[ks] = scale_g[((ks * 2 + (lane >> 5)) << L_SHIFT) + l];
#pragma unroll
            for (int j = 0; j < 8; ++j) {
                const int p = ks * 32 + lh * 8 + j;
                qv[ks][j] = Q[(p << L_SHIFT) + l];
            }
        }
        bf16x8 bfr[4];
#pragma unroll
        for (int ks = 0; ks < 4; ++ks)
#pragma unroll
            for (int j = 0; j < 8; ++j)
                bfr[ks][j] = (short)f2bf(sigm(qv[ks][j]) * scv[ks]);

        f32x4 acc[8];
#pragma unroll
        for (int mt = 0; mt < 8; ++mt)
            acc[mt] = *(const f32x4*)&bias[mt * 16 + lh * 4];

#pragma unroll
        for (int ks = 0; ks < 4; ++ks) {
#pragma unroll
            for (int mt = 0; mt < 8; ++mt) {
                const int row = mt * 16 + lq;
                const bf16x8 aA = *(const bf16x8*)&A_lds[row * 68 + ks * 16 + lh * 4];
                acc[mt] = __builtin_amdgcn_mfma_f32_16x16x32_bf16(aA, bfr[ks], acc[mt], 0, 0, 0);
            }
        }

#pragma unroll
        for (int mt = 0; mt < 8; ++mt) {
#pragma unroll
            for (int r = 0; r < 4; ++r) {
                const int dim = mt * 16 + lh * 4 + r;
                out[(dim << L_SHIFT) + l] = acc[mt][r];
            }
        }
    }
}

// ---------------------------------------------------------------------------
extern "C" void kernel_launch(void* const* d_in, const int* in_sizes, int n_in,
                              void* d_out, int out_size, void* d_ws, size_t ws_size,
                              hipStream_t stream) {
    const float* Q = (const float*)d_in[0];
    const float* K = (const float*)d_in[1];
    const float* V = (const float*)d_in[2];
    const float* W = (const float*)d_in[3];
    const float* B = (const float*)d_in[4];
    float* out = (float*)d_out;
    float* ws = (float*)d_ws;

    // workspace layout (floats) — every region written before read each call
    float* parts    = ws;                          // 1024*8*256 = 2097152
    unsigned* wkvb  = (unsigned*)(ws + 2097152);   // 8192 u32
    float* sep      = ws + 2105344;                // 1024*8 = 8192
    float* scale    = ws + 2113536;                // 8*L

    k12_fused<<<1024, 256, 0, stream>>>(Q, K, V, scale, sep, parts);
    k3_wkv<<<NHEAD, 256, 0, stream>>>(W, parts, sep, wkvb);
    k4_mfma<<<L_TOT / 128, 256, 0, stream>>>(Q, scale, wkvb, B, out);
}

// Round 15
// 179.566 us; speedup vs baseline: 1.2106x; 1.2106x over previous
//
#include <hip/hip_runtime.h>
#include <hip/hip_bf16.h>

#define L_TOT (1 << 18)       // 262144 positions
#define L_SHIFT 18
#define NHEAD 8
#define DHEAD 16
#define DMODEL 128
#define EPSF 1e-6f

typedef float f32x4 __attribute__((ext_vector_type(4)));
typedef short bf16x8 __attribute__((ext_vector_type(8)));

__device__ __forceinline__ float frcp(float x) { return __builtin_amdgcn_rcpf(x); }
__device__ __forceinline__ float sigm(float x) { return frcp(1.0f + __expf(-x)); }
__device__ __forceinline__ unsigned short f2bf(float f) {
    return (unsigned short)((__float_as_uint(f) + 0x8000u) >> 16);
}
__device__ __forceinline__ float bf2f(unsigned short u) {
    return __uint_as_float(((unsigned)u) << 16);
}

// sum across each aligned 4-lane quad (lanes s=0..3 share one l), bcast to all 4
__device__ __forceinline__ float qsum(float x) {
    x += __int_as_float(__builtin_amdgcn_update_dpp(0, __float_as_int(x), 0xB1, 0xf, 0xf, true)); // xor1
    x += __int_as_float(__builtin_amdgcn_update_dpp(0, __float_as_int(x), 0x4E, 0xf, 0xf, true)); // xor2
    return x;
}

// ---------------------------------------------------------------------------
// K1: per-position stats, direct-load (R8 proven structure, 48 VGPR).
// Block = 256 thr = 64 l's. Quad lanes s=0..3 share l = l0 + (t>>2);
// lane s owns d-slice {4s..4s+3} for all 8 heads: p = 16h + 4s + r.
// CHANGE vs R8: wbuf & scale stored as bf16 (halves aux write traffic; both
// are consumed only as bf16-MFMA-fragment inputs downstream).
// ---------------------------------------------------------------------------
__global__ __launch_bounds__(256) void k1_stats(
        const float* __restrict__ Q, const float* __restrict__ K,
        unsigned short* __restrict__ scale_o, unsigned short* __restrict__ wbuf,
        float* __restrict__ sep) {
    __shared__ float hredl[4][8];

    const int t = threadIdx.x;
    const int l0 = blockIdx.x * 64;
    const int c = t >> 2;              // 0..63: which l
    const int s = t & 3;               // d-slice
    const int l = l0 + c;

    // ---- issue all 64 loads up-front ----
    float qv[32], kvv[32];
#pragma unroll
    for (int h = 0; h < 8; ++h)
#pragma unroll
        for (int r = 0; r < 4; ++r) {
            const int p = h * 16 + s * 4 + r;
            qv[h * 4 + r]  = Q[(p << L_SHIFT) + l];
            kvv[h * 4 + r] = K[(p << L_SHIFT) + l];
        }

    // ---- sigmoid + pack (sigma(k)|sigma(q)) via v_perm ----
    unsigned a[32];
#pragma unroll
    for (int i = 0; i < 32; ++i) {
        const unsigned qu = __float_as_uint(sigm(qv[i])) + 0x8000u;
        const unsigned ku = __float_as_uint(sigm(kvv[i])) + 0x8000u;
        a[i] = __builtin_amdgcn_perm(ku, qu, 0x07060302u); // hi16(ku)|hi16(qu)
    }

    // head sums ks[d], qs[d] over h (in-register, this lane's 4 d's)
    float ks[4] = {0.f, 0.f, 0.f, 0.f}, qs[4] = {0.f, 0.f, 0.f, 0.f};
#pragma unroll
    for (int h = 0; h < 8; ++h)
#pragma unroll
        for (int j = 0; j < 4; ++j) {
            const unsigned u = a[h * 4 + j];
            qs[j] += __uint_as_float(u << 16);
            ks[j] += __uint_as_float(u & 0xffff0000u);
        }

    float kse[4], qse[4];
#pragma unroll
    for (int j = 0; j < 4; ++j) { kse[j] = ks[j] + EPSF; qse[j] = qs[j] + EPSF; }

    // si[h] = 1/sum_d sq*(ks+e);  so[h] = 1/sum_d sk*(qs+e)
    float si[8], so[8];
#pragma unroll
    for (int h = 0; h < 8; ++h) {
        float aq = 0.f, ak = 0.f;
#pragma unroll
        for (int j = 0; j < 4; ++j) {
            const unsigned u = a[h * 4 + j];
            aq += __uint_as_float(u << 16) * kse[j];
            ak += __uint_as_float(u & 0xffff0000u) * qse[j];
        }
        si[h] = frcp(qsum(aq));
        so[h] = frcp(qsum(ak));
    }

    // kso[d] = sum_h sk*so[h];  qsi[d] = sum_h sq*si[h]
    float kso[4] = {0.f, 0.f, 0.f, 0.f}, qsi[4] = {0.f, 0.f, 0.f, 0.f};
#pragma unroll
    for (int h = 0; h < 8; ++h)
#pragma unroll
        for (int j = 0; j < 4; ++j) {
            const unsigned u = a[h * 4 + j];
            kso[j] += __uint_as_float(u & 0xffff0000u) * so[h];
            qsi[j] += __uint_as_float(u << 16) * si[h];
        }
#pragma unroll
    for (int j = 0; j < 4; ++j) { kse[j] = kso[j] + EPSF; qse[j] = qsi[j] + EPSF; }

    // conserved sink/source; lane s finalizes h = 2s, 2s+1
    float e2[2], sc2[2];
#pragma unroll
    for (int h = 0; h < 8; ++h) {
        float aq = 0.f, ak = 0.f;
#pragma unroll
        for (int j = 0; j < 4; ++j) {
            const unsigned u = a[h * 4 + j];
            aq += __uint_as_float(u << 16) * kse[j];
            ak += __uint_as_float(u & 0xffff0000u) * qse[j];
        }
        const float ck = qsum(aq);
        float cs = qsum(ak);
        if ((h >> 1) == s) {
            cs = fminf(fmaxf(cs, -1.f), 1.f);
            e2[h & 1] = __expf(cs);
            sc2[h & 1] = sigm(ck) * si[h];
        }
    }

    // ---- bf16 coalesced stores ----
    wbuf[((2 * s + 0) << L_SHIFT) + l] = f2bf(e2[0]);
    wbuf[((2 * s + 1) << L_SHIFT) + l] = f2bf(e2[1]);
    scale_o[((2 * s + 0) << L_SHIFT) + l] = f2bf(sc2[0]);
    scale_o[((2 * s + 1) << L_SHIFT) + l] = f2bf(sc2[1]);

    // ---- block sumexp partials (f32, pre-quantization) ----
    float v0 = e2[0], v1 = e2[1];
    v0 += __shfl_xor(v0, 4, 64);  v1 += __shfl_xor(v1, 4, 64);
    v0 += __shfl_xor(v0, 8, 64);  v1 += __shfl_xor(v1, 8, 64);
    v0 += __shfl_xor(v0, 16, 64); v1 += __shfl_xor(v1, 16, 64);
    v0 += __shfl_xor(v0, 32, 64); v1 += __shfl_xor(v1, 32, 64);
    if ((t & 63) < 4) {
        const int w = t >> 6;
        hredl[w][2 * s + 0] = v0;
        hredl[w][2 * s + 1] = v1;
    }
    __syncthreads();
    if (t < 8)
        sep[blockIdx.x * 8 + t] = hredl[0][t] + hredl[1][t] + hredl[2][t] + hredl[3][t];
}

// ---------------------------------------------------------------------------
// K2 (MFMA, LDS-free): kv[h][d][m] = sum_l sig(K[16h+d][l])*w[h][l] * V[16h+m][l]
// grid = 8 heads x 128 blocks x 4 waves; wave owns 512 l's = 16 K-chunks of 32.
// w read as bf16. Deterministic: 4-wave LDS reduce -> parts[b*256+t].
// ---------------------------------------------------------------------------
__global__ __launch_bounds__(256) void k2_kv(
        const float* __restrict__ Kg, const float* __restrict__ Vg,
        const unsigned short* __restrict__ wg, float* __restrict__ parts) {
    __shared__ float kvred[4][256];
    const int b = blockIdx.x;
    const int h = b >> 7;
    const int blk = b & 127;
    const int t = threadIdx.x;
    const int wv = t >> 6, lane = t & 63;
    const int lq = lane & 15, lh = lane >> 4;

    const int rowKV = ((h * DHEAD + lq) << L_SHIFT);
    const int rowW  = (h << L_SHIFT);
    const int lbase = blk * 2048 + wv * 512 + lh * 8;

    f32x4 acc = {0.f, 0.f, 0.f, 0.f};
#pragma unroll 4
    for (int ch = 0; ch < 16; ++ch) {
        const int lo = lbase + ch * 32;
        const float4 ka = *(const float4*)&Kg[rowKV + lo];
        const float4 kb = *(const float4*)&Kg[rowKV + lo + 4];
        const float4 va = *(const float4*)&Vg[rowKV + lo];
        const float4 vb = *(const float4*)&Vg[rowKV + lo + 4];
        const ushort4 w0 = *(const ushort4*)&wg[rowW + lo];
        const ushort4 w1 = *(const ushort4*)&wg[rowW + lo + 4];
        bf16x8 af, bvf;
        af[0] = (short)f2bf(sigm(ka.x) * bf2f(w0.x));
        af[1] = (short)f2bf(sigm(ka.y) * bf2f(w0.y));
        af[2] = (short)f2bf(sigm(ka.z) * bf2f(w0.z));
        af[3] = (short)f2bf(sigm(ka.w) * bf2f(w0.w));
        af[4] = (short)f2bf(sigm(kb.x) * bf2f(w1.x));
        af[5] = (short)f2bf(sigm(kb.y) * bf2f(w1.y));
        af[6] = (short)f2bf(sigm(kb.z) * bf2f(w1.z));
        af[7] = (short)f2bf(sigm(kb.w) * bf2f(w1.w));
        bvf[0] = (short)f2bf(va.x);
        bvf[1] = (short)f2bf(va.y);
        bvf[2] = (short)f2bf(va.z);
        bvf[3] = (short)f2bf(va.w);
        bvf[4] = (short)f2bf(vb.x);
        bvf[5] = (short)f2bf(vb.y);
        bvf[6] = (short)f2bf(vb.z);
        bvf[7] = (short)f2bf(vb.w);
        acc = __builtin_amdgcn_mfma_f32_16x16x32_bf16(af, bvf, acc, 0, 0, 0);
    }

    // D: row d = lh*4+r, col m = lq -> flat d*16+m
#pragma unroll
    for (int r = 0; r < 4; ++r)
        kvred[wv][(lh * 4 + r) * 16 + lq] = acc[r];
    __syncthreads();
    parts[b * 256 + t] = kvred[0][t] + kvred[1][t] + kvred[2][t] + kvred[3][t];
}

// ---------------------------------------------------------------------------
// K3: reduce sep -> sumexp; reduce parts -> kv (fixed order, deterministic);
// emit Wkv as bf16-packed pairs wkvb[dim][p/2]. 8 blocks x 256 threads.
// ---------------------------------------------------------------------------
__global__ __launch_bounds__(256) void k3_wkv(
        const float* __restrict__ Wg, const float* __restrict__ parts,
        const float* __restrict__ sep, unsigned* __restrict__ wkvb) {
    const int hb = blockIdx.x;
    const int t = threadIdx.x;
    __shared__ float kvf[256];
    __shared__ float redl[4];

    float p = 0.f;
#pragma unroll
    for (int i = 0; i < 16; ++i) p += sep[(t + i * 256) * 8 + hb];   // 4096 k1 blocks
#pragma unroll
    for (int o = 32; o >= 1; o >>= 1) p += __shfl_xor(p, o, 64);
    if ((t & 63) == 0) redl[t >> 6] = p;

    float kacc = 0.f;
    for (int j = 0; j < 128; ++j)
        kacc += parts[(hb * 128 + j) * 256 + t];

    __syncthreads();
    const float s = (float)L_TOT / (redl[0] + redl[1] + redl[2] + redl[3]);
    kvf[t] = kacc * s;
    __syncthreads();

#pragma unroll
    for (int i = 0; i < 4; ++i) {
        const int j = t + i * 256;              // 0..1023
        const int dim = j & 127, prp = j >> 7;  // prp: 0..7 (pr pairs)
        float a0 = 0.f, a1 = 0.f;
#pragma unroll
        for (int mm = 0; mm < 16; ++mm) {
            const float wv = Wg[dim * 128 + hb * 16 + mm];
            a0 += wv * kvf[(2 * prp) * 16 + mm];
            a1 += wv * kvf[(2 * prp + 1) * 16 + mm];
        }
        wkvb[dim * 64 + hb * 8 + prp] = ((unsigned)f2bf(a1) << 16) | f2bf(a0);
    }
}

// ---------------------------------------------------------------------------
// K4 (MFMA): out[dim,l] = b[dim] + sum_p Wkv[dim][p] * g[p][l]
// scale read as bf16.
// ---------------------------------------------------------------------------
__global__ __launch_bounds__(256) void k4_mfma(
        const float* __restrict__ Q, const unsigned short* __restrict__ scale_g,
        const unsigned* __restrict__ wkvb, const float* __restrict__ bg,
        float* __restrict__ out) {
    __shared__ unsigned A_lds[128 * 68];     // 34.8 KB
    __shared__ float bias[128];
    const int t = threadIdx.x;

    // stage packed Wkv into LDS
#pragma unroll
    for (int i = 0; i < 8; ++i) {
        const int idx4 = t + i * 256;        // 0..2047 uint4's
        const uint4 v = ((const uint4*)wkvb)[idx4];
        const int row = idx4 >> 4, c4 = idx4 & 15;
        *(uint4*)&A_lds[row * 68 + c4 * 4] = v;
    }
    if (t < 128) bias[t] = bg[t];
    __syncthreads();

    const int w = t >> 6, lane = t & 63;
    const int lq = lane & 15, lh = lane >> 4;

#pragma unroll
    for (int ci = 0; ci < 2; ++ci) {
        const int l = blockIdx.x * 128 + ci * 64 + w * 16 + lq;

        // load Q + scale for all 4 K-steps
        float qv[4][8];
        float scv[4];
#pragma unroll
        for (int ks = 0; ks < 4; ++ks) {
            scv[ks] = bf2f(scale_g[((ks * 2 + (lane >> 5)) << L_SHIFT) + l]);
#pragma unroll
            for (int j = 0; j < 8; ++j) {
                const int p = ks * 32 + lh * 8 + j;
                qv[ks][j] = Q[(p << L_SHIFT) + l];
            }
        }
        bf16x8 bfr[4];
#pragma unroll
        for (int ks = 0; ks < 4; ++ks)
#pragma unroll
            for (int j = 0; j < 8; ++j)
                bfr[ks][j] = (short)f2bf(sigm(qv[ks][j]) * scv[ks]);

        f32x4 acc[8];
#pragma unroll
        for (int mt = 0; mt < 8; ++mt)
            acc[mt] = *(const f32x4*)&bias[mt * 16 + lh * 4];

#pragma unroll
        for (int ks = 0; ks < 4; ++ks) {
#pragma unroll
            for (int mt = 0; mt < 8; ++mt) {
                const int row = mt * 16 + lq;
                const bf16x8 aA = *(const bf16x8*)&A_lds[row * 68 + ks * 16 + lh * 4];
                acc[mt] = __builtin_amdgcn_mfma_f32_16x16x32_bf16(aA, bfr[ks], acc[mt], 0, 0, 0);
            }
        }

#pragma unroll
        for (int mt = 0; mt < 8; ++mt) {
#pragma unroll
            for (int r = 0; r < 4; ++r) {
                const int dim = mt * 16 + lh * 4 + r;
                out[(dim << L_SHIFT) + l] = acc[mt][r];
            }
        }
    }
}

// ---------------------------------------------------------------------------
extern "C" void kernel_launch(void* const* d_in, const int* in_sizes, int n_in,
                              void* d_out, int out_size, void* d_ws, size_t ws_size,
                              hipStream_t stream) {
    const float* Q = (const float*)d_in[0];
    const float* K = (const float*)d_in[1];
    const float* V = (const float*)d_in[2];
    const float* W = (const float*)d_in[3];
    const float* B = (const float*)d_in[4];
    float* out = (float*)d_out;
    float* ws = (float*)d_ws;

    // workspace layout — every region written before read each call
    float* parts          = ws;                               // 1024*256 = 262144 f32
    unsigned* wkvb        = (unsigned*)(ws + 262144);         // 8192 u32
    float* sep            = ws + 270336;                      // 4096*8 = 32768 f32
    unsigned short* scale = (unsigned short*)(ws + 303104);   // 8*L bf16
    unsigned short* wbuf  = (unsigned short*)(ws + 303104 + 4 * L_TOT); // 8*L bf16

    k1_stats<<<L_TOT / 64, 256, 0, stream>>>(Q, K, scale, wbuf, sep);
    k2_kv<<<NHEAD * 128, 256, 0, stream>>>(K, V, wbuf, parts);
    k3_wkv<<<NHEAD, 256, 0, stream>>>(W, parts, sep, wkvb);
    k4_mfma<<<L_TOT / 128, 256, 0, stream>>>(Q, scale, wkvb, B, out);
}